// Round 1
// baseline (3088.398 us; speedup 1.0000x reference)
//
#include <hip/hip_runtime.h>

#define NN   100000
#define NE   1600000
#define DD   64
#define LL   4
#define GG   512
#define OUTC 10
#define EPSV 1e-5f

// workspace layout (float offsets)
#define OFF_DEG    0           // NN floats (becomes dis after dis_kernel)
#define OFF_ENORM  102400      // NE floats
#define OFF_BUFA   1702400     // NN*DD floats (hw)
#define OFF_BUFB   8102400     // NN*DD floats (h / agg)
#define OFF_POOLED 14502400    // GG*LL*DD = 131072 floats
#define OFF_Z1     14633472    // GG*DD = 32768 floats
#define OFF_SUMS   14666240    // 128 floats (sum, sumsq)

__global__ void deg_kernel(const int* __restrict__ dst, float* __restrict__ deg) {
    int e = blockIdx.x * 256 + threadIdx.x;
    if (e < NE) atomicAdd(&deg[dst[e]], 1.0f);
}

__global__ void dis_kernel(float* __restrict__ deg) {
    int i = blockIdx.x * 256 + threadIdx.x;
    if (i < NN) deg[i] = rsqrtf(deg[i] + 1.0f);
}

__global__ void enorm_kernel(const int* __restrict__ src, const int* __restrict__ dst,
                             const float* __restrict__ dis, float* __restrict__ enorm) {
    int e = blockIdx.x * 256 + threadIdx.x;
    if (e < NE) enorm[e] = dis[src[e]] * dis[dst[e]];
}

// Fused: hw = h @ W ; agg_init = hw*snorm + bias. 16 rows per block, 256 threads.
// Safe in-place (agg may alias hin): each block reads only its own 16 rows into
// LDS before __syncthreads, writes only those rows after.
__global__ void gemm_kernel(const float* hin, const float* __restrict__ W,
                            const float* __restrict__ bias, const float* __restrict__ dis,
                            float* __restrict__ hw, float* agg) {
    __shared__ float Wsh[64 * 64];
    __shared__ float hs[16][64];
    int tid = threadIdx.x;
    int row0 = blockIdx.x * 16;
    #pragma unroll
    for (int i = 0; i < 16; ++i) Wsh[tid + i * 256] = W[tid + i * 256];
    #pragma unroll
    for (int i = 0; i < 4; ++i) {
        int idx = tid + i * 256;          // 0..1023
        int r = idx >> 6, c = idx & 63;
        int gr = row0 + r;
        hs[r][c] = (gr < NN) ? hin[gr * 64 + c] : 0.f;
    }
    __syncthreads();
    int q = tid >> 6;      // wave id 0..3 -> rows q*4..q*4+3
    int d = tid & 63;      // output column = lane
    float a0 = 0.f, a1 = 0.f, a2 = 0.f, a3 = 0.f;
    #pragma unroll
    for (int k = 0; k < 64; ++k) {
        float w = Wsh[k * 64 + d];        // lanes 0..63 -> 2-way bank alias (free)
        a0 = fmaf(hs[q * 4 + 0][k], w, a0);   // wave-uniform broadcast reads
        a1 = fmaf(hs[q * 4 + 1][k], w, a1);
        a2 = fmaf(hs[q * 4 + 2][k], w, a2);
        a3 = fmaf(hs[q * 4 + 3][k], w, a3);
    }
    float bd = bias[d];
    float accs[4] = {a0, a1, a2, a3};
    #pragma unroll
    for (int i = 0; i < 4; ++i) {
        int gr = row0 + q * 4 + i;
        if (gr < NN) {
            float s = dis[gr];
            hw[gr * 64 + d]  = accs[i];
            agg[gr * 64 + d] = accs[i] * (s * s) + bd;
        }
    }
}

// One wave per edge: lane = channel. Coalesced 256B gather + 256B atomic add.
__global__ void scatter_kernel(const float* __restrict__ hw, const float* __restrict__ enorm,
                               const int* __restrict__ src, const int* __restrict__ dst,
                               float* __restrict__ agg) {
    int e = blockIdx.x * 4 + (threadIdx.x >> 6);
    int lane = threadIdx.x & 63;
    if (e < NE) {
        int s = src[e];
        int t = dst[e];
        float en = enorm[e];
        float v = hw[s * 64 + lane] * en;
        atomicAdd(&agg[t * 64 + lane], v);
    }
}

// One wave per node: pooled[batch[n], l*64+lane] += h[n,lane]
__global__ void pool_kernel(const float* __restrict__ h, const int* __restrict__ batch,
                            float* __restrict__ pooled, int l) {
    int n = blockIdx.x * 4 + (threadIdx.x >> 6);
    int lane = threadIdx.x & 63;
    if (n < NN) {
        int g = batch[n];
        atomicAdd(&pooled[g * 256 + l * 64 + lane], h[n * 64 + lane]);
    }
}

// z1 = pooled @ W1 + b1 ; accumulate column sums / sumsq for batch-norm.
__global__ void mlp1_kernel(const float* __restrict__ pooled, const float* __restrict__ W1,
                            const float* __restrict__ b1, float* __restrict__ z1,
                            float* __restrict__ sums) {
    __shared__ float row[256];
    int g = blockIdx.x, d = threadIdx.x;   // 64 threads
    #pragma unroll
    for (int i = 0; i < 4; ++i) row[d + i * 64] = pooled[g * 256 + d + i * 64];
    __syncthreads();
    float acc = b1[d];
    #pragma unroll 8
    for (int k = 0; k < 256; ++k) acc = fmaf(row[k], W1[k * 64 + d], acc);
    z1[g * 64 + d] = acc;
    atomicAdd(&sums[d], acc);
    atomicAdd(&sums[64 + d], acc * acc);
}

// batch-norm + relu + out GEMM [512,64]@[64,10]
__global__ void mlp2_kernel(const float* __restrict__ z1, const float* __restrict__ sums,
                            const float* __restrict__ gamma, const float* __restrict__ beta,
                            const float* __restrict__ W2, const float* __restrict__ b2,
                            float* __restrict__ out) {
    int g = blockIdx.x, d = threadIdx.x;   // 64 threads = 1 wave
    float mean = sums[d] * (1.0f / 512.0f);
    float var  = sums[64 + d] * (1.0f / 512.0f) - mean * mean;
    float z = (z1[g * 64 + d] - mean) * rsqrtf(var + EPSV) * gamma[d] + beta[d];
    z = fmaxf(z, 0.0f);
    #pragma unroll
    for (int o = 0; o < OUTC; ++o) {
        float v = z * W2[d * OUTC + o];
        #pragma unroll
        for (int s = 32; s; s >>= 1) v += __shfl_xor(v, s, 64);
        if (d == 0) out[g * OUTC + o] = v + b2[o];
    }
}

extern "C" void kernel_launch(void* const* d_in, const int* in_sizes, int n_in,
                              void* d_out, int out_size, void* d_ws, size_t ws_size,
                              hipStream_t stream) {
    (void)in_sizes; (void)n_in; (void)out_size; (void)ws_size;
    const float* x     = (const float*)d_in[0];
    const int*   ei    = (const int*)d_in[1];
    const int*   src   = ei;
    const int*   dst   = ei + NE;
    const int*   batch = (const int*)d_in[2];
    const float* Wc    = (const float*)d_in[3];
    const float* bc    = (const float*)d_in[4];
    const float* W1    = (const float*)d_in[5];
    const float* b1    = (const float*)d_in[6];
    const float* gamma = (const float*)d_in[7];
    const float* beta  = (const float*)d_in[8];
    const float* W2    = (const float*)d_in[9];
    const float* b2    = (const float*)d_in[10];
    float* out = (float*)d_out;
    float* ws  = (float*)d_ws;

    float* deg    = ws + OFF_DEG;     // becomes dis in place
    float* enorm  = ws + OFF_ENORM;
    float* bufA   = ws + OFF_BUFA;    // hw
    float* bufB   = ws + OFF_BUFB;    // h / agg
    float* pooled = ws + OFF_POOLED;
    float* z1     = ws + OFF_Z1;
    float* sums   = ws + OFF_SUMS;

    hipMemsetAsync(deg, 0, NN * sizeof(float), stream);
    hipMemsetAsync(pooled, 0, (131072 + 32768 + 128) * sizeof(float), stream);

    deg_kernel<<<NE / 256, 256, 0, stream>>>(dst, deg);
    dis_kernel<<<(NN + 255) / 256, 256, 0, stream>>>(deg);
    enorm_kernel<<<NE / 256, 256, 0, stream>>>(src, dst, deg, enorm);

    const float* hin = x;
    for (int l = 0; l < LL; ++l) {
        gemm_kernel<<<NN / 16, 256, 0, stream>>>(hin, Wc + l * 4096, bc + l * 64,
                                                 deg, bufA, bufB);
        scatter_kernel<<<NE / 4, 256, 0, stream>>>(bufA, enorm, src, dst, bufB);
        pool_kernel<<<NN / 4, 256, 0, stream>>>(bufB, batch, pooled, l);
        hin = bufB;
    }

    mlp1_kernel<<<GG, 64, 0, stream>>>(pooled, W1, b1, z1, sums);
    mlp2_kernel<<<GG, 64, 0, stream>>>(z1, sums, gamma, beta, W2, b2, out);
}

// Round 2
// 1136.551 us; speedup vs baseline: 2.7173x; 2.7173x over previous
//
#include <hip/hip_runtime.h>

#define NN   100000
#define NE   1600000
#define DD   64
#define LL   4
#define GG   512
#define OUTC 10
#define EPSV 1e-5f

// workspace layout (float offsets). Total 14,631,088 floats = 58.5 MB
// (under the round-1 known-good 58.67 MB footprint).
#define OFF_RS    0          // int row_start[NN+1]
#define OFF_CSR   100016     // int csr_src[NE]
#define OFF_BUFA  1700016    // float hws[NN*DD]  (z1+sums reuse this after layers)
#define OFF_BUFB  8100016    // float h[NN*DD]
#define OFF_POOL  14500016   // float pooled[GG*LL*DD]; deg/cnt(int[NN]) live here pre-layers

__global__ void deg_count_kernel(const int* __restrict__ dst, int* __restrict__ deg) {
    int e = blockIdx.x * 256 + threadIdx.x;
    if (e < NE) atomicAdd(&deg[dst[e]], 1);
}

// single-block exclusive scan of deg[0..NN) -> rs[0..NN]
__global__ void scan_kernel(const int* __restrict__ deg, int* __restrict__ rs) {
    const int CH = 98;                       // 1024*98 >= NN
    int t = threadIdx.x;
    int lo = t * CH, hi = min(lo + CH, NN);
    int s = 0;
    for (int i = lo; i < hi; ++i) s += deg[i];
    __shared__ int ps[1024];
    ps[t] = s;
    __syncthreads();
    for (int off = 1; off < 1024; off <<= 1) {
        int v = (t >= off) ? ps[t - off] : 0;
        __syncthreads();
        ps[t] += v;
        __syncthreads();
    }
    int run = (t == 0) ? 0 : ps[t - 1];
    for (int i = lo; i < hi; ++i) { rs[i] = run; run += deg[i]; }
    if (t == 1023) rs[NN] = ps[1023];
}

__global__ void fill_kernel(const int* __restrict__ src, const int* __restrict__ dst,
                            const int* __restrict__ rs, int* __restrict__ cnt,
                            int* __restrict__ csr) {
    int e = blockIdx.x * 256 + threadIdx.x;
    if (e < NE) {
        int d = dst[e];
        int slot = rs[d] + atomicAdd(&cnt[d], 1);
        csr[slot] = src[e];
    }
}

// hws = (h @ W) * deg^{-1/2}.  16 rows/block, 256 threads. No aliasing.
__global__ __launch_bounds__(256)
void gemm_kernel(const float* __restrict__ hin, const float* __restrict__ W,
                 const int* __restrict__ rs, float* __restrict__ hws) {
    __shared__ float Wsh[64 * 64];
    __shared__ float hs[16][64];
    int tid = threadIdx.x;
    int row0 = blockIdx.x * 16;
    #pragma unroll
    for (int i = 0; i < 16; ++i) Wsh[tid + i * 256] = W[tid + i * 256];
    #pragma unroll
    for (int i = 0; i < 4; ++i) {
        int idx = tid + i * 256;
        int r = idx >> 6, c = idx & 63;
        int gr = row0 + r;
        hs[r][c] = (gr < NN) ? hin[gr * 64 + c] : 0.f;
    }
    __syncthreads();
    int q = tid >> 6;
    int d = tid & 63;
    float a0 = 0.f, a1 = 0.f, a2 = 0.f, a3 = 0.f;
    #pragma unroll
    for (int k = 0; k < 64; ++k) {
        float w = Wsh[k * 64 + d];
        a0 = fmaf(hs[q * 4 + 0][k], w, a0);
        a1 = fmaf(hs[q * 4 + 1][k], w, a1);
        a2 = fmaf(hs[q * 4 + 2][k], w, a2);
        a3 = fmaf(hs[q * 4 + 3][k], w, a3);
    }
    float accs[4] = {a0, a1, a2, a3};
    #pragma unroll
    for (int i = 0; i < 4; ++i) {
        int gr = row0 + q * 4 + i;
        if (gr < NN) {
            float di = rsqrtf((float)(rs[gr + 1] - rs[gr]) + 1.0f);
            hws[gr * 64 + d] = accs[i] * di;
        }
    }
}

// h[n] = deg^{-1/2}[n] * (hws[n] + sum_{j in nbr(n)} hws[src_j]) + b ; fused pooling.
__global__ __launch_bounds__(256)
void agg_kernel(const float* __restrict__ hws, const int* __restrict__ csr,
                const int* __restrict__ rs, const float* __restrict__ bias,
                const int* __restrict__ batch, float* __restrict__ h,
                float* __restrict__ pooled, int l) {
    int n = blockIdx.x * 4 + (threadIdx.x >> 6);
    int lane = threadIdx.x & 63;
    if (n >= NN) return;
    int j0 = rs[n], j1 = rs[n + 1];
    float di = rsqrtf((float)(j1 - j0) + 1.0f);
    float acc = hws[n * 64 + lane];
    int j = j0;
    for (; j + 1 < j1; j += 2) {
        int s0 = csr[j], s1 = csr[j + 1];
        float v0 = hws[s0 * 64 + lane];
        float v1 = hws[s1 * 64 + lane];
        acc += v0 + v1;
    }
    if (j < j1) acc += hws[csr[j] * 64 + lane];
    float hv = acc * di + bias[lane];
    h[n * 64 + lane] = hv;
    atomicAdd(&pooled[batch[n] * 256 + l * 64 + lane], hv);
}

__global__ void mlp1_kernel(const float* __restrict__ pooled, const float* __restrict__ W1,
                            const float* __restrict__ b1, float* __restrict__ z1,
                            float* __restrict__ sums) {
    __shared__ float row[256];
    int g = blockIdx.x, d = threadIdx.x;   // 64 threads
    #pragma unroll
    for (int i = 0; i < 4; ++i) row[d + i * 64] = pooled[g * 256 + d + i * 64];
    __syncthreads();
    float acc = b1[d];
    #pragma unroll 8
    for (int k = 0; k < 256; ++k) acc = fmaf(row[k], W1[k * 64 + d], acc);
    z1[g * 64 + d] = acc;
    atomicAdd(&sums[d], acc);
    atomicAdd(&sums[64 + d], acc * acc);
}

__global__ void mlp2_kernel(const float* __restrict__ z1, const float* __restrict__ sums,
                            const float* __restrict__ gamma, const float* __restrict__ beta,
                            const float* __restrict__ W2, const float* __restrict__ b2,
                            float* __restrict__ out) {
    int g = blockIdx.x, d = threadIdx.x;   // 64 threads = 1 wave
    float mean = sums[d] * (1.0f / 512.0f);
    float var  = sums[64 + d] * (1.0f / 512.0f) - mean * mean;
    float z = (z1[g * 64 + d] - mean) * rsqrtf(var + EPSV) * gamma[d] + beta[d];
    z = fmaxf(z, 0.0f);
    #pragma unroll
    for (int o = 0; o < OUTC; ++o) {
        float v = z * W2[d * OUTC + o];
        #pragma unroll
        for (int s = 32; s; s >>= 1) v += __shfl_xor(v, s, 64);
        if (d == 0) out[g * OUTC + o] = v + b2[o];
    }
}

extern "C" void kernel_launch(void* const* d_in, const int* in_sizes, int n_in,
                              void* d_out, int out_size, void* d_ws, size_t ws_size,
                              hipStream_t stream) {
    (void)in_sizes; (void)n_in; (void)out_size; (void)ws_size;
    const float* x     = (const float*)d_in[0];
    const int*   ei    = (const int*)d_in[1];
    const int*   src   = ei;
    const int*   dst   = ei + NE;
    const int*   batch = (const int*)d_in[2];
    const float* Wc    = (const float*)d_in[3];
    const float* bc    = (const float*)d_in[4];
    const float* W1    = (const float*)d_in[5];
    const float* b1    = (const float*)d_in[6];
    const float* gamma = (const float*)d_in[7];
    const float* beta  = (const float*)d_in[8];
    const float* W2    = (const float*)d_in[9];
    const float* b2    = (const float*)d_in[10];
    float* out = (float*)d_out;
    float* ws  = (float*)d_ws;

    int*   rs     = (int*)(ws + OFF_RS);
    int*   csr    = (int*)(ws + OFF_CSR);
    float* bufA   = ws + OFF_BUFA;              // hws
    float* bufB   = ws + OFF_BUFB;              // h
    float* pooled = ws + OFF_POOL;
    int*   degcnt = (int*)(ws + OFF_POOL);      // deg, then cnt (dead before pooling)
    float* z1     = bufA;                        // reused after layers
    float* sums   = bufA + GG * DD;

    // --- build CSR (once per launch) ---
    hipMemsetAsync(degcnt, 0, NN * sizeof(int), stream);
    deg_count_kernel<<<NE / 256, 256, 0, stream>>>(dst, degcnt);
    scan_kernel<<<1, 1024, 0, stream>>>(degcnt, rs);
    hipMemsetAsync(degcnt, 0, NN * sizeof(int), stream);   // cnt
    fill_kernel<<<NE / 256, 256, 0, stream>>>(src, dst, rs, degcnt, csr);

    // --- zero pooled (overlays the dead deg/cnt region) ---
    hipMemsetAsync(pooled, 0, GG * LL * DD * sizeof(float), stream);

    // --- layers ---
    const float* hin = x;
    for (int l = 0; l < LL; ++l) {
        gemm_kernel<<<NN / 16, 256, 0, stream>>>(hin, Wc + l * 4096, rs, bufA);
        agg_kernel<<<NN / 4, 256, 0, stream>>>(bufA, csr, rs, bc + l * 64,
                                               batch, bufB, pooled, l);
        hin = bufB;
    }

    // --- MLP head (z1/sums overlay dead bufA) ---
    hipMemsetAsync(sums, 0, 128 * sizeof(float), stream);
    mlp1_kernel<<<GG, 64, 0, stream>>>(pooled, W1, b1, z1, sums);
    mlp2_kernel<<<GG, 64, 0, stream>>>(z1, sums, gamma, beta, W2, b2, out);
}

// Round 3
// 925.471 us; speedup vs baseline: 3.3371x; 1.2281x over previous
//
#include <hip/hip_runtime.h>

#define NN   100000
#define NE   1600000
#define DD   64
#define LL   4
#define GG   512
#define OUTC 10
#define EPSV 1e-5f

// workspace layout (float offsets). Total 14,631,088 floats = 58.5 MB.
#define OFF_RS    0          // int row_start[NN+1]
#define OFF_CSR   100016     // int csr_src[NE]   (first NN ints double as scan temp 'loc')
#define OFF_BUFA  1700016    // float hws[NN*DD]  (scan bsum/boff + z1/sums reuse this)
#define OFF_BUFB  8100016    // float h[NN*DD]
#define OFF_POOL  14500016   // float pooled[GG*LL*DD]; deg/cnt(int[NN]) live here pre-layers

__global__ void deg_count_kernel(const int* __restrict__ dst, int* __restrict__ deg) {
    int e = blockIdx.x * 256 + threadIdx.x;
    if (e < NE) atomicAdd(&deg[dst[e]], 1);
}

// two-level scan: per-block exclusive scan + block totals
__global__ void scan1_kernel(const int* __restrict__ deg, int* __restrict__ loc,
                             int* __restrict__ bsum) {
    int t = threadIdx.x;
    int i = blockIdx.x * 1024 + t;
    int v = (i < NN) ? deg[i] : 0;
    __shared__ int ps[1024];
    ps[t] = v;
    __syncthreads();
    #pragma unroll
    for (int off = 1; off < 1024; off <<= 1) {
        int u = (t >= off) ? ps[t - off] : 0;
        __syncthreads();
        ps[t] += u;
        __syncthreads();
    }
    if (i < NN) loc[i] = ps[t] - v;          // local exclusive
    if (t == 1023) bsum[blockIdx.x] = ps[1023];
}

__global__ void scan2_kernel(const int* __restrict__ bsum, int* __restrict__ boff) {
    int t = threadIdx.x;                      // 128 threads, 98 valid
    int v = (t < 98) ? bsum[t] : 0;
    __shared__ int ps[128];
    ps[t] = v;
    __syncthreads();
    #pragma unroll
    for (int off = 1; off < 128; off <<= 1) {
        int u = (t >= off) ? ps[t - off] : 0;
        __syncthreads();
        ps[t] += u;
        __syncthreads();
    }
    if (t < 98) boff[t] = ps[t] - v;          // exclusive block offsets
    if (t == 127) boff[98] = ps[127];         // grand total
}

__global__ void scan3_kernel(const int* __restrict__ loc, const int* __restrict__ boff,
                             int* __restrict__ rs) {
    int i = blockIdx.x * 1024 + threadIdx.x;
    if (i < NN) rs[i] = loc[i] + boff[i >> 10];
    if (i == NN) rs[NN] = boff[98];
}

__global__ void fill_kernel(const int* __restrict__ src, const int* __restrict__ dst,
                            const int* __restrict__ rs, int* __restrict__ cnt,
                            int* __restrict__ csr) {
    int e = blockIdx.x * 256 + threadIdx.x;
    if (e < NE) {
        int d = dst[e];
        int slot = rs[d] + atomicAdd(&cnt[d], 1);
        csr[slot] = src[e];
    }
}

// hws = (h @ W) * deg^{-1/2}.  16 rows/block, 256 threads.
__global__ __launch_bounds__(256)
void gemm_kernel(const float* __restrict__ hin, const float* __restrict__ W,
                 const int* __restrict__ rs, float* __restrict__ hws) {
    __shared__ float Wsh[64 * 64];
    __shared__ float hs[16][64];
    int tid = threadIdx.x;
    int row0 = blockIdx.x * 16;
    #pragma unroll
    for (int i = 0; i < 16; ++i) Wsh[tid + i * 256] = W[tid + i * 256];
    #pragma unroll
    for (int i = 0; i < 4; ++i) {
        int idx = tid + i * 256;
        int r = idx >> 6, c = idx & 63;
        int gr = row0 + r;
        hs[r][c] = (gr < NN) ? hin[gr * 64 + c] : 0.f;
    }
    __syncthreads();
    int q = tid >> 6;
    int d = tid & 63;
    float a0 = 0.f, a1 = 0.f, a2 = 0.f, a3 = 0.f;
    #pragma unroll
    for (int k = 0; k < 64; ++k) {
        float w = Wsh[k * 64 + d];
        a0 = fmaf(hs[q * 4 + 0][k], w, a0);
        a1 = fmaf(hs[q * 4 + 1][k], w, a1);
        a2 = fmaf(hs[q * 4 + 2][k], w, a2);
        a3 = fmaf(hs[q * 4 + 3][k], w, a3);
    }
    float accs[4] = {a0, a1, a2, a3};
    #pragma unroll
    for (int i = 0; i < 4; ++i) {
        int gr = row0 + q * 4 + i;
        if (gr < NN) {
            float di = rsqrtf((float)(rs[gr + 1] - rs[gr]) + 1.0f);
            hws[gr * 64 + d] = accs[i] * di;
        }
    }
}

// h[n] = deg^{-1/2}[n] * (hws[n] + sum_{j in nbr(n)} hws[src_j]) + b ; fused pooling.
__global__ __launch_bounds__(256)
void agg_kernel(const float* __restrict__ hws, const int* __restrict__ csr,
                const int* __restrict__ rs, const float* __restrict__ bias,
                const int* __restrict__ batch, float* __restrict__ h,
                float* __restrict__ pooled, int l) {
    int n = blockIdx.x * 4 + (threadIdx.x >> 6);
    int lane = threadIdx.x & 63;
    if (n >= NN) return;
    int j0 = rs[n], j1 = rs[n + 1];
    float di = rsqrtf((float)(j1 - j0) + 1.0f);
    float acc = hws[n * 64 + lane];
    int j = j0;
    for (; j + 3 < j1; j += 4) {                 // 4 independent gathers in flight
        int s0 = csr[j], s1 = csr[j + 1], s2 = csr[j + 2], s3 = csr[j + 3];
        float v0 = hws[s0 * 64 + lane];
        float v1 = hws[s1 * 64 + lane];
        float v2 = hws[s2 * 64 + lane];
        float v3 = hws[s3 * 64 + lane];
        acc += (v0 + v1) + (v2 + v3);
    }
    for (; j < j1; ++j) acc += hws[csr[j] * 64 + lane];
    float hv = acc * di + bias[lane];
    h[n * 64 + lane] = hv;
    atomicAdd(&pooled[batch[n] * 256 + l * 64 + lane], hv);
}

__global__ void mlp1_kernel(const float* __restrict__ pooled, const float* __restrict__ W1,
                            const float* __restrict__ b1, float* __restrict__ z1,
                            float* __restrict__ sums) {
    __shared__ float row[256];
    int g = blockIdx.x, d = threadIdx.x;   // 64 threads
    #pragma unroll
    for (int i = 0; i < 4; ++i) row[d + i * 64] = pooled[g * 256 + d + i * 64];
    __syncthreads();
    float acc = b1[d];
    #pragma unroll 8
    for (int k = 0; k < 256; ++k) acc = fmaf(row[k], W1[k * 64 + d], acc);
    z1[g * 64 + d] = acc;
    atomicAdd(&sums[d], acc);
    atomicAdd(&sums[64 + d], acc * acc);
}

__global__ void mlp2_kernel(const float* __restrict__ z1, const float* __restrict__ sums,
                            const float* __restrict__ gamma, const float* __restrict__ beta,
                            const float* __restrict__ W2, const float* __restrict__ b2,
                            float* __restrict__ out) {
    int g = blockIdx.x, d = threadIdx.x;   // 64 threads = 1 wave
    float mean = sums[d] * (1.0f / 512.0f);
    float var  = sums[64 + d] * (1.0f / 512.0f) - mean * mean;
    float z = (z1[g * 64 + d] - mean) * rsqrtf(var + EPSV) * gamma[d] + beta[d];
    z = fmaxf(z, 0.0f);
    #pragma unroll
    for (int o = 0; o < OUTC; ++o) {
        float v = z * W2[d * OUTC + o];
        #pragma unroll
        for (int s = 32; s; s >>= 1) v += __shfl_xor(v, s, 64);
        if (d == 0) out[g * OUTC + o] = v + b2[o];
    }
}

extern "C" void kernel_launch(void* const* d_in, const int* in_sizes, int n_in,
                              void* d_out, int out_size, void* d_ws, size_t ws_size,
                              hipStream_t stream) {
    (void)in_sizes; (void)n_in; (void)out_size; (void)ws_size;
    const float* x     = (const float*)d_in[0];
    const int*   ei    = (const int*)d_in[1];
    const int*   src   = ei;
    const int*   dst   = ei + NE;
    const int*   batch = (const int*)d_in[2];
    const float* Wc    = (const float*)d_in[3];
    const float* bc    = (const float*)d_in[4];
    const float* W1    = (const float*)d_in[5];
    const float* b1    = (const float*)d_in[6];
    const float* gamma = (const float*)d_in[7];
    const float* beta  = (const float*)d_in[8];
    const float* W2    = (const float*)d_in[9];
    const float* b2    = (const float*)d_in[10];
    float* out = (float*)d_out;
    float* ws  = (float*)d_ws;

    int*   rs     = (int*)(ws + OFF_RS);
    int*   csr    = (int*)(ws + OFF_CSR);
    int*   loc    = (int*)(ws + OFF_CSR);       // scan temp, dead before fill
    float* bufA   = ws + OFF_BUFA;              // hws
    float* bufB   = ws + OFF_BUFB;              // h
    float* pooled = ws + OFF_POOL;
    int*   degcnt = (int*)(ws + OFF_POOL);      // deg, then cnt (dead before pooling)
    int*   bsum   = (int*)bufA;                 // scan temps, dead before gemm
    int*   boff   = (int*)bufA + 128;
    float* z1     = bufA;                       // reused after layers
    float* sums   = bufA + GG * DD;

    // --- build CSR (once per launch) ---
    hipMemsetAsync(degcnt, 0, NN * sizeof(int), stream);
    deg_count_kernel<<<NE / 256, 256, 0, stream>>>(dst, degcnt);
    scan1_kernel<<<98, 1024, 0, stream>>>(degcnt, loc, bsum);
    scan2_kernel<<<1, 128, 0, stream>>>(bsum, boff);
    scan3_kernel<<<99, 1024, 0, stream>>>(loc, boff, rs);
    hipMemsetAsync(degcnt, 0, NN * sizeof(int), stream);   // cnt
    fill_kernel<<<NE / 256, 256, 0, stream>>>(src, dst, rs, degcnt, csr);

    // --- zero pooled (overlays the dead deg/cnt region) ---
    hipMemsetAsync(pooled, 0, GG * LL * DD * sizeof(float), stream);

    // --- layers ---
    const float* hin = x;
    for (int l = 0; l < LL; ++l) {
        gemm_kernel<<<NN / 16, 256, 0, stream>>>(hin, Wc + l * 4096, rs, bufA);
        agg_kernel<<<NN / 4, 256, 0, stream>>>(bufA, csr, rs, bc + l * 64,
                                               batch, bufB, pooled, l);
        hin = bufB;
    }

    // --- MLP head (z1/sums overlay dead bufA) ---
    hipMemsetAsync(sums, 0, 128 * sizeof(float), stream);
    mlp1_kernel<<<GG, 64, 0, stream>>>(pooled, W1, b1, z1, sums);
    mlp2_kernel<<<GG, 64, 0, stream>>>(z1, sums, gamma, beta, W2, b2, out);
}

// Round 4
// 731.143 us; speedup vs baseline: 4.2241x; 1.2658x over previous
//
#include <hip/hip_runtime.h>

#define NN   100000
#define NE   1600000
#define DD   64
#define LL   4
#define GG   512
#define OUTC 10
#define EPSV 1e-5f
#define PARTSZ 12500   // NN/8 dst-partition size

// workspace layout (float offsets). Total 14,631,088 floats = 58.5 MB.
#define OFF_RS    0          // int row_start[NN+1]
#define OFF_CSR   100016     // int csr_src[NE]   (first NN ints double as scan temp 'loc')
#define OFF_BUFA  1700016    // float t ping  (scan bsum/boff + z1/sums overlay)
#define OFF_BUFB  8100016    // float t pong
#define OFF_POOL  14500016   // float pooled[GG*LL*DD]; deg/cnt(int[NN]) overlay pre-layers

// ---- CSR build: XCD-partitioned histogram + fill (blockIdx&7 ~ XCD round-robin;
//      heuristic only affects locality, never correctness) ----
__global__ void deg_part_kernel(const int* __restrict__ dst, int* __restrict__ deg) {
    int p   = blockIdx.x & 7;
    int sub = blockIdx.x >> 3;
    int nb  = gridDim.x >> 3;
    for (int e = sub * 256 + threadIdx.x; e < NE; e += nb * 256) {
        int d = dst[e];
        if (d / PARTSZ == p) atomicAdd(&deg[d], 1);
    }
}

__global__ void scan1_kernel(const int* __restrict__ deg, int* __restrict__ loc,
                             int* __restrict__ bsum) {
    int t = threadIdx.x;
    int i = blockIdx.x * 1024 + t;
    int v = (i < NN) ? deg[i] : 0;
    __shared__ int ps[1024];
    ps[t] = v;
    __syncthreads();
    #pragma unroll
    for (int off = 1; off < 1024; off <<= 1) {
        int u = (t >= off) ? ps[t - off] : 0;
        __syncthreads();
        ps[t] += u;
        __syncthreads();
    }
    if (i < NN) loc[i] = ps[t] - v;
    if (t == 1023) bsum[blockIdx.x] = ps[1023];
}

__global__ void scan2_kernel(const int* __restrict__ bsum, int* __restrict__ boff) {
    int t = threadIdx.x;                      // 128 threads, 98 valid
    int v = (t < 98) ? bsum[t] : 0;
    __shared__ int ps[128];
    ps[t] = v;
    __syncthreads();
    #pragma unroll
    for (int off = 1; off < 128; off <<= 1) {
        int u = (t >= off) ? ps[t - off] : 0;
        __syncthreads();
        ps[t] += u;
        __syncthreads();
    }
    if (t < 98) boff[t] = ps[t] - v;
    if (t == 127) boff[98] = ps[127];
}

__global__ void scan3_kernel(const int* __restrict__ loc, const int* __restrict__ boff,
                             int* __restrict__ rs) {
    int i = blockIdx.x * 1024 + threadIdx.x;
    if (i < NN) rs[i] = loc[i] + boff[i >> 10];
    if (i == NN) rs[NN] = boff[98];
}

__global__ void fill_part_kernel(const int* __restrict__ src, const int* __restrict__ dst,
                                 const int* __restrict__ rs, int* __restrict__ cnt,
                                 int* __restrict__ csr) {
    int p   = blockIdx.x & 7;
    int sub = blockIdx.x >> 3;
    int nb  = gridDim.x >> 3;
    for (int e = sub * 256 + threadIdx.x; e < NE; e += nb * 256) {
        int d = dst[e];
        if (d / PARTSZ == p) {
            int slot = rs[d] + atomicAdd(&cnt[d], 1);
            csr[slot] = src[e];
        }
    }
}

// t0 = x * deg^{-1/2}, vectorized float4
__global__ void t0_kernel(const float* __restrict__ x, const int* __restrict__ rs,
                          float* __restrict__ t0) {
    int i = blockIdx.x * 256 + threadIdx.x;   // over NN*16 quads
    int n = i >> 4;
    float di = rsqrtf((float)(rs[n + 1] - rs[n]) + 1.0f);
    float4 v = ((const float4*)x)[i];
    v.x *= di; v.y *= di; v.z *= di; v.w *= di;
    ((float4*)t0)[i] = v;
}

// Fused layer: u = t[n] + sum_nbr t[src]; v = dis*u; h' = v@W + b;
// tout = dis*h'; pooled[batch[n]] += h'.  16 nodes/block (4 per wave).
__global__ __launch_bounds__(256)
void layer_kernel(const float* __restrict__ t, const int* __restrict__ csr,
                  const int* __restrict__ rs, const float* __restrict__ W,
                  const float* __restrict__ bias, const int* __restrict__ batch,
                  float* __restrict__ tout, float* __restrict__ pooled, int l) {
    __shared__ float Wsh[64 * 64];
    __shared__ float vsh[4][4][64];
    int tid = threadIdx.x;
    // bijective XCD chunk-swizzle: consecutive node-chunks stay on one XCD
    int nwg = gridDim.x;                 // 6250
    int q = nwg >> 3, r = nwg & 7;       // 781, 2
    int xcd = blockIdx.x & 7, sub = blockIdx.x >> 3;
    int bid = (xcd < r ? xcd * (q + 1) : r * (q + 1) + (xcd - r) * q) + sub;

    #pragma unroll
    for (int i = 0; i < 16; ++i) Wsh[tid + i * 256] = W[tid + i * 256];

    int w = tid >> 6, lane = tid & 63;
    int n0 = bid * 16 + w * 4;
    float dis[4];
    #pragma unroll
    for (int s = 0; s < 4; ++s) {
        int n = n0 + s;
        int j0 = rs[n], j1 = rs[n + 1];
        float di = rsqrtf((float)(j1 - j0) + 1.0f);
        dis[s] = di;
        float acc = t[n * 64 + lane];
        int j = j0;
        for (; j + 3 < j1; j += 4) {
            int s0 = csr[j], s1 = csr[j + 1], s2 = csr[j + 2], s3 = csr[j + 3];
            float v0 = t[s0 * 64 + lane];
            float v1 = t[s1 * 64 + lane];
            float v2 = t[s2 * 64 + lane];
            float v3 = t[s3 * 64 + lane];
            acc += (v0 + v1) + (v2 + v3);
        }
        for (; j < j1; ++j) acc += t[csr[j] * 64 + lane];
        vsh[w][s][lane] = acc * di;
    }
    __syncthreads();
    float a0 = 0.f, a1 = 0.f, a2 = 0.f, a3 = 0.f;
    #pragma unroll
    for (int k = 0; k < 64; ++k) {
        float wv = Wsh[k * 64 + lane];
        a0 = fmaf(vsh[w][0][k], wv, a0);
        a1 = fmaf(vsh[w][1][k], wv, a1);
        a2 = fmaf(vsh[w][2][k], wv, a2);
        a3 = fmaf(vsh[w][3][k], wv, a3);
    }
    float bd = bias[lane];
    float accs[4] = {a0, a1, a2, a3};
    #pragma unroll
    for (int s = 0; s < 4; ++s) {
        int n = n0 + s;
        float h = accs[s] + bd;
        tout[n * 64 + lane] = h * dis[s];
        atomicAdd(&pooled[batch[n] * 256 + l * 64 + lane], h);
    }
}

__global__ void mlp1_kernel(const float* __restrict__ pooled, const float* __restrict__ W1,
                            const float* __restrict__ b1, float* __restrict__ z1,
                            float* __restrict__ sums) {
    __shared__ float row[256];
    int g = blockIdx.x, d = threadIdx.x;   // 64 threads
    #pragma unroll
    for (int i = 0; i < 4; ++i) row[d + i * 64] = pooled[g * 256 + d + i * 64];
    __syncthreads();
    float acc = b1[d];
    #pragma unroll 8
    for (int k = 0; k < 256; ++k) acc = fmaf(row[k], W1[k * 64 + d], acc);
    z1[g * 64 + d] = acc;
    atomicAdd(&sums[d], acc);
    atomicAdd(&sums[64 + d], acc * acc);
}

__global__ void mlp2_kernel(const float* __restrict__ z1, const float* __restrict__ sums,
                            const float* __restrict__ gamma, const float* __restrict__ beta,
                            const float* __restrict__ W2, const float* __restrict__ b2,
                            float* __restrict__ out) {
    int g = blockIdx.x, d = threadIdx.x;   // 64 threads = 1 wave
    float mean = sums[d] * (1.0f / 512.0f);
    float var  = sums[64 + d] * (1.0f / 512.0f) - mean * mean;
    float z = (z1[g * 64 + d] - mean) * rsqrtf(var + EPSV) * gamma[d] + beta[d];
    z = fmaxf(z, 0.0f);
    #pragma unroll
    for (int o = 0; o < OUTC; ++o) {
        float v = z * W2[d * OUTC + o];
        #pragma unroll
        for (int s = 32; s; s >>= 1) v += __shfl_xor(v, s, 64);
        if (d == 0) out[g * OUTC + o] = v + b2[o];
    }
}

extern "C" void kernel_launch(void* const* d_in, const int* in_sizes, int n_in,
                              void* d_out, int out_size, void* d_ws, size_t ws_size,
                              hipStream_t stream) {
    (void)in_sizes; (void)n_in; (void)out_size; (void)ws_size;
    const float* x     = (const float*)d_in[0];
    const int*   ei    = (const int*)d_in[1];
    const int*   src   = ei;
    const int*   dst   = ei + NE;
    const int*   batch = (const int*)d_in[2];
    const float* Wc    = (const float*)d_in[3];
    const float* bc    = (const float*)d_in[4];
    const float* W1    = (const float*)d_in[5];
    const float* b1    = (const float*)d_in[6];
    const float* gamma = (const float*)d_in[7];
    const float* beta  = (const float*)d_in[8];
    const float* W2    = (const float*)d_in[9];
    const float* b2    = (const float*)d_in[10];
    float* out = (float*)d_out;
    float* ws  = (float*)d_ws;

    int*   rs     = (int*)(ws + OFF_RS);
    int*   csr    = (int*)(ws + OFF_CSR);
    int*   loc    = (int*)(ws + OFF_CSR);       // scan temp, dead before fill
    float* bufA   = ws + OFF_BUFA;
    float* bufB   = ws + OFF_BUFB;
    float* pooled = ws + OFF_POOL;
    int*   degcnt = (int*)(ws + OFF_POOL);      // deg, then cnt (dead before pooling)
    int*   bsum   = (int*)bufA;                 // scan temps, dead before t0
    int*   boff   = (int*)bufA + 128;
    float* z1     = bufA;                       // overlay, dead after layers
    float* sums   = bufA + GG * DD;

    // --- build CSR ---
    hipMemsetAsync(degcnt, 0, NN * sizeof(int), stream);
    deg_part_kernel<<<1024, 256, 0, stream>>>(dst, degcnt);
    scan1_kernel<<<98, 1024, 0, stream>>>(degcnt, loc, bsum);
    scan2_kernel<<<1, 128, 0, stream>>>(bsum, boff);
    scan3_kernel<<<99, 1024, 0, stream>>>(loc, boff, rs);
    hipMemsetAsync(degcnt, 0, NN * sizeof(int), stream);   // cnt
    fill_part_kernel<<<1024, 256, 0, stream>>>(src, dst, rs, degcnt, csr);

    // --- t0 = x * dis ; zero pooled (overlays dead deg/cnt) ---
    t0_kernel<<<NN * 16 / 256, 256, 0, stream>>>(x, rs, bufA);
    hipMemsetAsync(pooled, 0, GG * LL * DD * sizeof(float), stream);

    // --- fused layers (ping-pong) ---
    float* tin = bufA; float* tot = bufB;
    for (int l = 0; l < LL; ++l) {
        layer_kernel<<<NN / 16, 256, 0, stream>>>(tin, csr, rs, Wc + l * 4096,
                                                  bc + l * 64, batch, tot, pooled, l);
        float* tmp = tin; tin = tot; tot = tmp;
    }

    // --- MLP head (z1/sums overlay dead bufA) ---
    hipMemsetAsync(sums, 0, 128 * sizeof(float), stream);
    mlp1_kernel<<<GG, 64, 0, stream>>>(pooled, W1, b1, z1, sums);
    mlp2_kernel<<<GG, 64, 0, stream>>>(z1, sums, gamma, beta, W2, b2, out);
}